// Round 1
// 725.879 us; speedup vs baseline: 1.0764x; 1.0764x over previous
//
#include <hip/hip_runtime.h>

// Conv2D valid cross-correlation via MFMA bf16 hi/lo split (3-term, ~1e-4 abs err).
// x(64,1024,1024) fp32 * k(16,16) fp32 -> out(64,1009,1009) fp32.
//
// Formulation: per kernel row ki, one 16x16x32 bf16 MFMA chain with
//   A(m, t) = Xpatch[rowbase + m + ki][colwin + t]      (m = lane&15, t = 8*(lane>>4)+j)
//   B(t, n) = K(ki, t - n) for 0 <= t-n < 16, else 0    (Toeplitz; built once into VGPRs)
//   D(m, n) += sum_t A*B  ==> out rows m, cols n.
// fp32 precision recovered with x = xh + xl, k = kh + kl; terms xh*kh + xh*kl + xl*kh.
//
// Block: 256 thr = 4 waves (2x2), tile 64 rows x 128 cols; per wave 32x64 (mr=2 x cn=4).
// LDS: Ah/Al bf16 patch 79 x 152 (stride 152: 16B-aligned rows, 2-way max bank conflict)
//      + 256-entry kernel limb tables. 49,056 B total (< 64 KB static limit).
// Main loop is barrier-free: B frags live in 128 VGPRs; 256 ds_read_b128 + 384 MFMAs.

#define CONV_H  1024
#define CONV_W  1024
#define CONV_OH 1009
#define CONV_OW 1009

#define BM 64                 // output rows per block
#define BN 128                // output cols per block
#define PATCH_R (BM + 15)     // 79 input rows staged
#define PATCH_C (BN + 16)     // 144 input cols staged (max col index used = 143)
#define LDS_S   152           // padded LDS row stride in elements (bytes=304, dwords=76 ≡ 12 mod 32 -> 2-way)

typedef __attribute__((ext_vector_type(8))) short short8;
typedef __attribute__((ext_vector_type(4))) float f32x4;

__device__ __forceinline__ unsigned short bf16_rne(float f) {
    union { float f; unsigned int u; } v; v.f = f;
    unsigned int r = v.u + 0x7fffu + ((v.u >> 16) & 1u);
    return (unsigned short)(r >> 16);
}
__device__ __forceinline__ float bf16_f32(unsigned short h) {
    union { unsigned int u; float f; } v; v.u = ((unsigned int)h) << 16;
    return v.f;
}

__global__ __launch_bounds__(256, 2)
void conv2d_mfma_bf16x3(const float* __restrict__ x,
                        const float* __restrict__ kern,
                        float* __restrict__ out) {
    __shared__ unsigned short Ah[PATCH_R * LDS_S];   // 24,016 B
    __shared__ unsigned short Al[PATCH_R * LDS_S];   // 24,016 B
    __shared__ unsigned short Khi[256];              // 512 B
    __shared__ unsigned short Klo[256];              // 512 B

    const int tid  = threadIdx.x;
    const int lane = tid & 63;
    const int w    = tid >> 6;      // wave 0..3
    const int wm   = w >> 1;        // row half   (32 output rows)
    const int wn   = w & 1;         // col half   (64 output cols)
    const int n16  = lane & 15;     // M-row (A) / N-col (B,D) index
    const int g    = lane >> 4;     // k-group: k = 8*g + j

    const int b  = blockIdx.z;
    const int I0 = blockIdx.y * BM;
    const int J0 = blockIdx.x * BN;

    // ---- kernel limb tables (1 KB) ----
    if (tid < 256) {
        float kv = kern[tid];
        unsigned short h = bf16_rne(kv);
        Khi[tid] = h;
        Klo[tid] = bf16_rne(kv - bf16_f32(h));
    }
    __syncthreads();

    // ---- build Toeplitz B fragments into registers: bh/bl[ki], k-slot = 8g+j -> kj = 8g+j-n ----
    short8 bh[16], bl[16];
    #pragma unroll
    for (int ki = 0; ki < 16; ++ki) {
        #pragma unroll
        for (int j = 0; j < 8; ++j) {
            const int kj   = 8 * g + j - n16;
            const bool ok  = (unsigned)kj < 16u;
            const int idx  = ki * 16 + (ok ? kj : 0);
            bh[ki][j] = ok ? (short)Khi[idx] : (short)0;
            bl[ki][j] = ok ? (short)Klo[idx] : (short)0;
        }
    }

    // ---- stage input patch (79 x 144 used) as bf16 hi/lo limbs ----
    const float* xb = x + (size_t)b * ((size_t)CONV_H * CONV_W);
    for (int idx = tid; idx < PATCH_R * (PATCH_C / 4); idx += 256) {
        const int r  = idx / (PATCH_C / 4);
        const int c4 = (idx - r * (PATCH_C / 4)) * 4;
        const int gr = I0 + r;
        const int gc = J0 + c4;
        float4 v = make_float4(0.f, 0.f, 0.f, 0.f);
        if (gr < CONV_H) {
            const float* row = xb + (size_t)gr * CONV_W;
            if (gc + 3 < CONV_W) {
                v = *(const float4*)(row + gc);
            } else {
                if (gc + 0 < CONV_W) v.x = row[gc + 0];
                if (gc + 1 < CONV_W) v.y = row[gc + 1];
                if (gc + 2 < CONV_W) v.z = row[gc + 2];
                if (gc + 3 < CONV_W) v.w = row[gc + 3];
            }
        }
        const unsigned short h0 = bf16_rne(v.x), h1 = bf16_rne(v.y),
                             h2 = bf16_rne(v.z), h3 = bf16_rne(v.w);
        ushort4 hv = make_ushort4(h0, h1, h2, h3);
        ushort4 lv = make_ushort4(bf16_rne(v.x - bf16_f32(h0)),
                                  bf16_rne(v.y - bf16_f32(h1)),
                                  bf16_rne(v.z - bf16_f32(h2)),
                                  bf16_rne(v.w - bf16_f32(h3)));
        *(ushort4*)&Ah[r * LDS_S + c4] = hv;
        *(ushort4*)&Al[r * LDS_S + c4] = lv;
    }
    __syncthreads();

    // ---- main loop: barrier-free, fully unrolled. 384 MFMAs, 256 ds_read_b128 ----
    f32x4 acc[2][4];
    #pragma unroll
    for (int mr = 0; mr < 2; ++mr)
        #pragma unroll
        for (int cn = 0; cn < 4; ++cn)
            acc[mr][cn] = (f32x4){0.f, 0.f, 0.f, 0.f};

    #pragma unroll
    for (int ki = 0; ki < 16; ++ki) {
        #pragma unroll
        for (int mr = 0; mr < 2; ++mr) {
            const int prow = 32 * wm + 16 * mr + n16 + ki;   // patch row this lane reads
            const int base = prow * LDS_S + 64 * wn + 8 * g;
            #pragma unroll
            for (int cn = 0; cn < 4; ++cn) {
                const int off = base + 16 * cn;
                const short8 ah = *(const short8*)&Ah[off];
                const short8 al = *(const short8*)&Al[off];
                acc[mr][cn] = __builtin_amdgcn_mfma_f32_16x16x32_bf16(ah, bh[ki], acc[mr][cn], 0, 0, 0);
                acc[mr][cn] = __builtin_amdgcn_mfma_f32_16x16x32_bf16(ah, bl[ki], acc[mr][cn], 0, 0, 0);
                acc[mr][cn] = __builtin_amdgcn_mfma_f32_16x16x32_bf16(al, bh[ki], acc[mr][cn], 0, 0, 0);
            }
        }
    }

    // ---- store: D col = lane&15, row = 4*(lane>>4)+reg (verified C/D layout) ----
    float* ob = out + (size_t)b * ((size_t)CONV_OH * CONV_OW);
    #pragma unroll
    for (int mr = 0; mr < 2; ++mr) {
        #pragma unroll
        for (int cn = 0; cn < 4; ++cn) {
            const int gj = J0 + 64 * wn + 16 * cn + n16;
            #pragma unroll
            for (int r = 0; r < 4; ++r) {
                const int gi = I0 + 32 * wm + 16 * mr + 4 * g + r;
                if (gi < CONV_OH && gj < CONV_OW)
                    ob[(size_t)gi * CONV_OW + gj] = acc[mr][cn][r];
            }
        }
    }
}

extern "C" void kernel_launch(void* const* d_in, const int* in_sizes, int n_in,
                              void* d_out, int out_size, void* d_ws, size_t ws_size,
                              hipStream_t stream) {
    const float* x    = (const float*)d_in[0];
    const float* kern = (const float*)d_in[1];
    float* out        = (float*)d_out;

    dim3 grid((CONV_OW + BN - 1) / BN,    // 8
              (CONV_OH + BM - 1) / BM,    // 16
              64);                        // batch
    dim3 block(256);
    conv2d_mfma_bf16x3<<<grid, block, 0, stream>>>(x, kern, out);
}

// Round 2
// 600.355 us; speedup vs baseline: 1.3015x; 1.2091x over previous
//
#include <hip/hip_runtime.h>

// Conv2D valid cross-correlation via MFMA bf16 hi/lo split (3-term, ~1e-4 abs err).
// x(64,1024,1024) fp32 * k(16,16) fp32 -> out(64,1009,1009) fp32.
//
// Per kernel row ki: D(m,n) += sum_t A(m,t)*B(t,n), 16x16x32 bf16 MFMA.
//   A(m,t) = Xpatch[rowbase + m + ki][colwin + t]   (from LDS, conflict-free b128)
//   B(t,n) = K(ki, t-n) Toeplitz                    (from a prebuilt GLOBAL table)
//
// Round-2 change: B fragments are NOT built in-kernel. Previous version's
// VGPR_Count=120 proved the compiler rematerialized bh/bl per-iteration as
// lane-scattered ds_read_u16 (-> 3.45e7 bank conflicts, latency-bound loop).
// A tiny pre-kernel now writes the per-lane-layout B table (2 limb x 16 ki x
// 64 lane x 8 bf16 = 32 KB) to a static __device__ array; the main loop does
// 2 aligned global_load_dwordx4 per ki (L2-resident). LDS holds only the A
// patch (48 KB) -> 3 blocks/CU; __launch_bounds__(256,3) pins the allocator.

#define CONV_H  1024
#define CONV_W  1024
#define CONV_OH 1009
#define CONV_OW 1009

#define BM 64                 // output rows per block
#define BN 128                // output cols per block
#define PATCH_R (BM + 15)     // 79 input rows staged
#define PATCH_C (BN + 16)     // 144 input cols staged
#define LDS_S   152           // LDS row stride (elems): 76 dwords -> balanced banks, 16B-aligned rows

typedef __attribute__((ext_vector_type(8))) short short8;
typedef __attribute__((ext_vector_type(4))) float f32x4;

// [limb][ki][lane][8] bf16 B-fragments in exact MFMA per-lane layout. 32 KB.
__device__ __align__(16) unsigned short g_btab[2 * 16 * 64 * 8];

__device__ __forceinline__ unsigned short bf16_rne(float f) {
    union { float f; unsigned int u; } v; v.f = f;
    unsigned int r = v.u + 0x7fffu + ((v.u >> 16) & 1u);
    return (unsigned short)(r >> 16);
}
__device__ __forceinline__ float bf16_f32(unsigned short h) {
    union { unsigned int u; float f; } v; v.u = ((unsigned int)h) << 16;
    return v.f;
}

// ---- pre-kernel: build the Toeplitz B table (one 64-thread block) ----
__global__ void build_btab_kernel(const float* __restrict__ kern) {
    const int lane = threadIdx.x & 63;
    const int n16  = lane & 15;
    const int g    = lane >> 4;
    for (int ki = 0; ki < 16; ++ki) {
        unsigned short vh[8], vl[8];
        #pragma unroll
        for (int j = 0; j < 8; ++j) {
            const int kj = 8 * g + j - n16;          // k-slot 8g+j maps to kernel col (8g+j) - n
            const float kv = ((unsigned)kj < 16u) ? kern[ki * 16 + kj] : 0.f;
            const unsigned short h = bf16_rne(kv);
            vh[j] = h;
            vl[j] = bf16_rne(kv - bf16_f32(h));
        }
        unsigned short* ph = &g_btab[((0 * 16 + ki) * 64 + lane) * 8];
        unsigned short* pl = &g_btab[((1 * 16 + ki) * 64 + lane) * 8];
        #pragma unroll
        for (int j = 0; j < 8; ++j) { ph[j] = vh[j]; pl[j] = vl[j]; }
    }
}

__global__ __launch_bounds__(256, 3)
void conv2d_mfma_bf16x3(const float* __restrict__ x,
                        float* __restrict__ out) {
    __shared__ unsigned short Ah[PATCH_R * LDS_S];   // 24,016 B
    __shared__ unsigned short Al[PATCH_R * LDS_S];   // 24,016 B  -> 48 KB total, 3 blocks/CU

    const int tid  = threadIdx.x;
    const int lane = tid & 63;
    const int w    = tid >> 6;      // wave 0..3
    const int wm   = w >> 1;        // row half   (32 output rows)
    const int wn   = w & 1;         // col half   (64 output cols)
    const int n16  = lane & 15;     // M-row (A) / N-col (B,D) index
    const int g    = lane >> 4;     // k-group: k = 8*g + j

    const int b  = blockIdx.z;
    const int I0 = blockIdx.y * BM;
    const int J0 = blockIdx.x * BN;

    // ---- stage input patch (79 x 144 used) as bf16 hi/lo limbs ----
    const float* xb = x + (size_t)b * ((size_t)CONV_H * CONV_W);
    for (int idx = tid; idx < PATCH_R * (PATCH_C / 4); idx += 256) {
        const int r  = idx / (PATCH_C / 4);
        const int c4 = (idx - r * (PATCH_C / 4)) * 4;
        const int gr = I0 + r;
        const int gc = J0 + c4;
        float4 v = make_float4(0.f, 0.f, 0.f, 0.f);
        if (gr < CONV_H) {
            const float* row = xb + (size_t)gr * CONV_W;
            if (gc + 3 < CONV_W) {
                v = *(const float4*)(row + gc);
            } else {
                if (gc + 0 < CONV_W) v.x = row[gc + 0];
                if (gc + 1 < CONV_W) v.y = row[gc + 1];
                if (gc + 2 < CONV_W) v.z = row[gc + 2];
                if (gc + 3 < CONV_W) v.w = row[gc + 3];
            }
        }
        const unsigned short h0 = bf16_rne(v.x), h1 = bf16_rne(v.y),
                             h2 = bf16_rne(v.z), h3 = bf16_rne(v.w);
        ushort4 hv = make_ushort4(h0, h1, h2, h3);
        ushort4 lv = make_ushort4(bf16_rne(v.x - bf16_f32(h0)),
                                  bf16_rne(v.y - bf16_f32(h1)),
                                  bf16_rne(v.z - bf16_f32(h2)),
                                  bf16_rne(v.w - bf16_f32(h3)));
        *(ushort4*)&Ah[r * LDS_S + c4] = hv;
        *(ushort4*)&Al[r * LDS_S + c4] = lv;
    }
    __syncthreads();

    // ---- main loop: per ki, 2 global b128 B-loads (L2-hit) + 16 ds_read_b128 + 24 MFMA ----
    f32x4 acc[2][4];
    #pragma unroll
    for (int mr = 0; mr < 2; ++mr)
        #pragma unroll
        for (int cn = 0; cn < 4; ++cn)
            acc[mr][cn] = (f32x4){0.f, 0.f, 0.f, 0.f};

    const unsigned short* btl = g_btab + lane * 8;   // per-lane base; +512 ushorts per ki, +8192 for lo limb

    for (int ki = 0; ki < 16; ++ki) {
        const short8 bhf = *(const short8*)(btl + ki * 512);
        const short8 blf = *(const short8*)(btl + 8192 + ki * 512);

        #pragma unroll
        for (int mr = 0; mr < 2; ++mr) {
            const int prow = 32 * wm + 16 * mr + n16 + ki;   // patch row this lane reads
            const int base = prow * LDS_S + 64 * wn + 8 * g;
            #pragma unroll
            for (int cn = 0; cn < 4; ++cn) {
                const int off = base + 16 * cn;
                const short8 ah = *(const short8*)&Ah[off];
                const short8 al = *(const short8*)&Al[off];
                acc[mr][cn] = __builtin_amdgcn_mfma_f32_16x16x32_bf16(ah, bhf, acc[mr][cn], 0, 0, 0);
                acc[mr][cn] = __builtin_amdgcn_mfma_f32_16x16x32_bf16(ah, blf, acc[mr][cn], 0, 0, 0);
                acc[mr][cn] = __builtin_amdgcn_mfma_f32_16x16x32_bf16(al, bhf, acc[mr][cn], 0, 0, 0);
            }
        }
    }

    // ---- store: D col = lane&15, row = 4*(lane>>4)+reg ----
    float* ob = out + (size_t)b * ((size_t)CONV_OH * CONV_OW);
    #pragma unroll
    for (int mr = 0; mr < 2; ++mr) {
        #pragma unroll
        for (int cn = 0; cn < 4; ++cn) {
            const int gj = J0 + 64 * wn + 16 * cn + n16;
            #pragma unroll
            for (int r = 0; r < 4; ++r) {
                const int gi = I0 + 32 * wm + 16 * mr + 4 * g + r;
                if (gi < CONV_OH && gj < CONV_OW)
                    ob[(size_t)gi * CONV_OW + gj] = acc[mr][cn][r];
            }
        }
    }
}

extern "C" void kernel_launch(void* const* d_in, const int* in_sizes, int n_in,
                              void* d_out, int out_size, void* d_ws, size_t ws_size,
                              hipStream_t stream) {
    const float* x    = (const float*)d_in[0];
    const float* kern = (const float*)d_in[1];
    float* out        = (float*)d_out;

    build_btab_kernel<<<dim3(1), dim3(64), 0, stream>>>(kern);

    dim3 grid((CONV_OW + BN - 1) / BN,    // 8
              (CONV_OH + BM - 1) / BM,    // 16
              64);                        // batch
    dim3 block(256);
    conv2d_mfma_bf16x3<<<grid, block, 0, stream>>>(x, out);
}

// Round 3
// 540.838 us; speedup vs baseline: 1.4447x; 1.1100x over previous
//
#include <hip/hip_runtime.h>

// Conv2D valid cross-correlation via MFMA bf16 hi/lo split (3-term, ~1e-4 abs err).
// x(64,1024,1024) fp32 * k(16,16) fp32 -> out(64,1009,1009) fp32.
//
// Per kernel row ki: D(m,n) += sum_t A(m,t)*B(t,n), 16x16x32 bf16 MFMA.
//   A(m,t) = Xpatch[rowbase + m + ki][colwin + t]   (LDS, stride-152 b128 reads at the
//            b128 bank floor: ~12cy/wave-instr, 2-way quad aliasing = structural min)
//   B(t,n) = K(ki, t-n) Toeplitz                    (prebuilt GLOBAL table, L1/L2-hit)
//
// Round-3 change: occupancy. R2 counters: MfmaUtil 29%, est. LDS-busy ~53%, occupancy
// 33% -> latency-bound, no pipe saturated. Same 64x128 tile now uses 512-thread blocks
// (8 waves, per-wave 16 rows x 64 cols), LDS unchanged 48 KB -> 3 blocks/CU * 8 waves
// = 24 waves/CU (75%). __launch_bounds__(512,6) pins regs <=85 (current 68).

#define CONV_H  1024
#define CONV_W  1024
#define CONV_OH 1009
#define CONV_OW 1009

#define BM 64                 // output rows per block
#define BN 128                // output cols per block
#define PATCH_R (BM + 15)     // 79 input rows staged
#define PATCH_C (BN + 16)     // 144 input cols staged
#define LDS_S   152           // LDS row stride (elems): 76 dwords -> balanced bank quads

typedef __attribute__((ext_vector_type(8))) short short8;
typedef __attribute__((ext_vector_type(4))) float f32x4;

// [limb][ki][lane][8] bf16 B-fragments in exact MFMA per-lane layout. 32 KB.
__device__ __align__(16) unsigned short g_btab[2 * 16 * 64 * 8];

__device__ __forceinline__ unsigned short bf16_rne(float f) {
    union { float f; unsigned int u; } v; v.f = f;
    unsigned int r = v.u + 0x7fffu + ((v.u >> 16) & 1u);
    return (unsigned short)(r >> 16);
}
__device__ __forceinline__ float bf16_f32(unsigned short h) {
    union { unsigned int u; float f; } v; v.u = ((unsigned int)h) << 16;
    return v.f;
}

// ---- pre-kernel: build the Toeplitz B table (one 64-thread block) ----
__global__ void build_btab_kernel(const float* __restrict__ kern) {
    const int lane = threadIdx.x & 63;
    const int n16  = lane & 15;
    const int g    = lane >> 4;
    for (int ki = 0; ki < 16; ++ki) {
        unsigned short vh[8], vl[8];
        #pragma unroll
        for (int j = 0; j < 8; ++j) {
            const int kj = 8 * g + j - n16;          // k-slot 8g+j -> kernel col (8g+j) - n
            const float kv = ((unsigned)kj < 16u) ? kern[ki * 16 + kj] : 0.f;
            const unsigned short h = bf16_rne(kv);
            vh[j] = h;
            vl[j] = bf16_rne(kv - bf16_f32(h));
        }
        unsigned short* ph = &g_btab[((0 * 16 + ki) * 64 + lane) * 8];
        unsigned short* pl = &g_btab[((1 * 16 + ki) * 64 + lane) * 8];
        #pragma unroll
        for (int j = 0; j < 8; ++j) { ph[j] = vh[j]; pl[j] = vl[j]; }
    }
}

__global__ __launch_bounds__(512, 6)
void conv2d_mfma_bf16x3(const float* __restrict__ x,
                        float* __restrict__ out) {
    __shared__ unsigned short Ah[PATCH_R * LDS_S];   // 24,016 B
    __shared__ unsigned short Al[PATCH_R * LDS_S];   // 24,016 B  -> 48 KB, 3 blocks/CU

    const int tid  = threadIdx.x;
    const int lane = tid & 63;
    const int w    = tid >> 6;      // wave 0..7
    const int wm   = w >> 1;        // row quarter (16 output rows each)
    const int wn   = w & 1;         // col half    (64 output cols each)
    const int n16  = lane & 15;     // M-row (A) / N-col (B,D) index
    const int g    = lane >> 4;     // k-group: k = 8*g + j

    const int b  = blockIdx.z;
    const int I0 = blockIdx.y * BM;
    const int J0 = blockIdx.x * BN;

    // ---- stage input patch (79 x 144 used) as bf16 hi/lo limbs ----
    const float* xb = x + (size_t)b * ((size_t)CONV_H * CONV_W);
    for (int idx = tid; idx < PATCH_R * (PATCH_C / 4); idx += 512) {
        const int r  = idx / (PATCH_C / 4);
        const int c4 = (idx - r * (PATCH_C / 4)) * 4;
        const int gr = I0 + r;
        const int gc = J0 + c4;
        float4 v = make_float4(0.f, 0.f, 0.f, 0.f);
        if (gr < CONV_H) {
            const float* row = xb + (size_t)gr * CONV_W;
            if (gc + 3 < CONV_W) {
                v = *(const float4*)(row + gc);
            } else {
                if (gc + 0 < CONV_W) v.x = row[gc + 0];
                if (gc + 1 < CONV_W) v.y = row[gc + 1];
                if (gc + 2 < CONV_W) v.z = row[gc + 2];
                if (gc + 3 < CONV_W) v.w = row[gc + 3];
            }
        }
        const unsigned short h0 = bf16_rne(v.x), h1 = bf16_rne(v.y),
                             h2 = bf16_rne(v.z), h3 = bf16_rne(v.w);
        ushort4 hv = make_ushort4(h0, h1, h2, h3);
        ushort4 lv = make_ushort4(bf16_rne(v.x - bf16_f32(h0)),
                                  bf16_rne(v.y - bf16_f32(h1)),
                                  bf16_rne(v.z - bf16_f32(h2)),
                                  bf16_rne(v.w - bf16_f32(h3)));
        *(ushort4*)&Ah[r * LDS_S + c4] = hv;
        *(ushort4*)&Al[r * LDS_S + c4] = lv;
    }
    __syncthreads();

    // ---- main loop: per ki, 2 global b128 B-loads (cache-hit) + 8 ds_read_b128 + 12 MFMA ----
    f32x4 acc[4];
    #pragma unroll
    for (int cn = 0; cn < 4; ++cn)
        acc[cn] = (f32x4){0.f, 0.f, 0.f, 0.f};

    const unsigned short* btl = g_btab + lane * 8;   // +512 ushorts per ki; +8192 for lo limb

    for (int ki = 0; ki < 16; ++ki) {
        const short8 bhf = *(const short8*)(btl + ki * 512);
        const short8 blf = *(const short8*)(btl + 8192 + ki * 512);

        const int prow = 16 * wm + n16 + ki;         // patch row this lane reads
        const int base = prow * LDS_S + 64 * wn + 8 * g;
        #pragma unroll
        for (int cn = 0; cn < 4; ++cn) {
            const int off = base + 16 * cn;
            const short8 ah = *(const short8*)&Ah[off];
            const short8 al = *(const short8*)&Al[off];
            acc[cn] = __builtin_amdgcn_mfma_f32_16x16x32_bf16(ah, bhf, acc[cn], 0, 0, 0);
            acc[cn] = __builtin_amdgcn_mfma_f32_16x16x32_bf16(ah, blf, acc[cn], 0, 0, 0);
            acc[cn] = __builtin_amdgcn_mfma_f32_16x16x32_bf16(al, bhf, acc[cn], 0, 0, 0);
        }
    }

    // ---- store: D col = lane&15, row = 4*(lane>>4)+reg ----
    float* ob = out + (size_t)b * ((size_t)CONV_OH * CONV_OW);
    #pragma unroll
    for (int cn = 0; cn < 4; ++cn) {
        const int gj = J0 + 64 * wn + 16 * cn + n16;
        #pragma unroll
        for (int r = 0; r < 4; ++r) {
            const int gi = I0 + 16 * wm + 4 * g + r;
            if (gi < CONV_OH && gj < CONV_OW)
                ob[(size_t)gi * CONV_OW + gj] = acc[cn][r];
        }
    }
}

extern "C" void kernel_launch(void* const* d_in, const int* in_sizes, int n_in,
                              void* d_out, int out_size, void* d_ws, size_t ws_size,
                              hipStream_t stream) {
    const float* x    = (const float*)d_in[0];
    const float* kern = (const float*)d_in[1];
    float* out        = (float*)d_out;

    build_btab_kernel<<<dim3(1), dim3(64), 0, stream>>>(kern);

    dim3 grid((CONV_OW + BN - 1) / BN,    // 8
              (CONV_OH + BM - 1) / BM,    // 16
              64);                        // batch
    dim3 block(512);
    conv2d_mfma_bf16x3<<<grid, block, 0, stream>>>(x, out);
}